// Round 18
// baseline (654.392 us; speedup 1.0000x reference)
//
#include <hip/hip_runtime.h>

#define SEQ   512
#define NTHR  1024
#define NBLK  256

typedef _Float16 f16x8 __attribute__((ext_vector_type(8)));
typedef float    f32x4 __attribute__((ext_vector_type(4)));

#define MFMA(a, b, c) __builtin_amdgcn_mfma_f32_16x16x32_f16((a), (b), (c), 0, 0, 0)

__device__ __forceinline__ float sig_(float x) {
    return __builtin_amdgcn_rcpf(1.0f + __builtin_amdgcn_exp2f(x * -1.4426950408889634f));
}
// sign-safe tanh via 2*sigmoid(2x)-1
__device__ __forceinline__ float tanh_(float x) {
    return fmaf(2.0f, __builtin_amdgcn_rcpf(1.0f + __builtin_amdgcn_exp2f(x * -2.8853900817779268f)), -1.0f);
}

// Two-phase staggered schedule. Each SIMD hosts one wave per layer (w&3).
// Cycle k = two barrier-separated sub-ticks:
//   Sub A: layers {0,2} MFMA(tM)   ; layers {1,3} GATES(tM-1)
//   Sub B: layers {1,3} MFMA(tM)   ; layers {0,2} GATES(tM)  + L3 combine
// Skews tM = k - {0,1,3,4}. So every half-tick each SIMD runs 2 MFMA-phase
// waves (matrix pipe) AND 2 gate-phase waves (VALU/trans) -> pipes overlap
// across waves (sum -> max), which the single-phase lockstep never achieved.
// h ring: slot = t&1 (per-layer step). All producer->consumer pairs are
// barrier-separated; same-interval accesses land on opposite parities.

#define MFMA_PHASE(T)                                                          \
    {                                                                          \
        const int pS = (((T) & 1) ^ 1) << 11;                                  \
        f16x8 b0, b1, b2, b3;                                                  \
        if (ell == 0) {                                                        \
            b0 = *(const f16x8*)(hb + pS + sfA0);                              \
            b1 = *(const f16x8*)(hb + pS + sfA1);                              \
            if (lam == 0) xf[0] = (_Float16)xrow[T];                           \
            b2 = xf; b3 = xf;                                                  \
        } else {                                                               \
            const int pI = ((T) & 1) << 11;                                    \
            b0 = *(const f16x8*)(hb + pI + inA0);                              \
            b1 = *(const f16x8*)(hb + pI + inA1);                              \
            b2 = *(const f16x8*)(hb + pS + sfA0);                              \
            b3 = *(const f16x8*)(hb + pS + sfA1);                              \
        }                                                                      \
        A0 = MFMA(wf[0][0], b0, biasv[0]);                                     \
        A1 = MFMA(wf[1][0], b0, biasv[1]);                                     \
        A2 = MFMA(wf[2][0], b0, biasv[2]);                                     \
        A3 = MFMA(wf[3][0], b0, biasv[3]);                                     \
        A0 = MFMA(wf[0][1], b1, A0);  A1 = MFMA(wf[1][1], b1, A1);             \
        A2 = MFMA(wf[2][1], b1, A2);  A3 = MFMA(wf[3][1], b1, A3);             \
        A0 = MFMA(wf[0][2], b2, A0);  A1 = MFMA(wf[1][2], b2, A1);             \
        A2 = MFMA(wf[2][2], b2, A2);  A3 = MFMA(wf[3][2], b2, A3);             \
        A0 = MFMA(wf[0][3], b3, A0);  A1 = MFMA(wf[1][3], b3, A1);             \
        A2 = MFMA(wf[2][3], b3, A2);  A3 = MFMA(wf[3][3], b3, A3);             \
    }

#define GATES_PHASE(T)                                                         \
    {                                                                          \
        const f32x4 s01 = k1b ? A1 : A0;                                       \
        const f32x4 s23 = k1b ? A3 : A2;                                       \
        const f32x4 aK  = k2b ? s23 : s01;                                     \
        const float gi = sig_(aK[0]);                                          \
        const float gf = sig_(aK[1]);                                          \
        const float gg = tanh_(aK[2]);                                         \
        const float go = sig_(aK[3]);                                          \
        cstK = fmaf(gf, cstK, gi * gg);                                        \
        const float hn = go * tanh_(cstK);                                     \
        *(_Float16*)(hb + (((T) & 1) << 11) + wrKS) = (_Float16)hn;            \
        if (ell == 3) {                                                        \
            float v1 = hn, v2 = hn * hn, v3 = hn * gwK;                        \
            v1 += __shfl_xor(v1, 4, 64);  v2 += __shfl_xor(v2, 4, 64);  v3 += __shfl_xor(v3, 4, 64);  \
            v1 += __shfl_xor(v1, 8, 64);  v2 += __shfl_xor(v2, 8, 64);  v3 += __shfl_xor(v3, 8, 64);  \
            v1 += __shfl_xor(v1, 16, 64); v2 += __shfl_xor(v2, 16, 64); v3 += __shfl_xor(v3, 16, 64); \
            v1 += __shfl_xor(v1, 32, 64); v2 += __shfl_xor(v2, 32, 64); v3 += __shfl_xor(v3, 32, 64); \
            if (bc < 4) {                                                      \
                float* pp = &part[(T) & 15][om][bc][0];                        \
                pp[0] = v1; pp[1] = v2; pp[2] = v3;                            \
            }                                                                  \
        }                                                                      \
    }

// LN combine: run by the 4 layer-3 waves only (256 threads), inside their
// MFMA half-tick (VALU hides under their own in-flight MFMAs).
#define COMBINE3(TG)                                                           \
    {                                                                          \
        const int sl = om * 2 + (lane >> 5);                                   \
        const int b  = (lane >> 3) & 3;                                        \
        const int j  = lane & 7;                                               \
        const int slot = ((TG) - 7 + sl) & 15;                                 \
        float u1 = 0.f, u2 = 0.f, u3 = 0.f;                                    \
        if (j < 4) {                                                           \
            u1 = part[slot][j][b][0];                                          \
            u2 = part[slot][j][b][1];                                          \
            u3 = part[slot][j][b][2];                                          \
        }                                                                      \
        u1 += __shfl_xor(u1, 1, 64); u2 += __shfl_xor(u2, 1, 64); u3 += __shfl_xor(u3, 1, 64); \
        u1 += __shfl_xor(u1, 2, 64); u2 += __shfl_xor(u2, 2, 64); u3 += __shfl_xor(u3, 2, 64); \
        if (j == 0) {                                                          \
            const float mu = u1 * (1.0f / 64.0f);                              \
            float var = fmaf(u2, 1.0f / 64.0f, -mu * mu);                      \
            var = fmaxf(var, 0.0f);                                            \
            const float rs = rsqrtf(var + 1e-5f);                              \
            out[(bb * 4 + b) * SEQ + ((TG) - 7) + sl] = fmaf(rs, fmaf(-mu, Sgw, u3), Sbw); \
        }                                                                      \
    }

__global__ __launch_bounds__(NTHR, 4) void lstm4_stag(
    const float* __restrict__ x,
    const float* __restrict__ W0, const float* __restrict__ B0,
    const float* __restrict__ W1, const float* __restrict__ B1,
    const float* __restrict__ W2, const float* __restrict__ B2,
    const float* __restrict__ W3, const float* __restrict__ B3,
    const float* __restrict__ ln_g, const float* __restrict__ ln_b,
    const float* __restrict__ Wout, const float* __restrict__ bout,
    float* __restrict__ out)
{
    __shared__ __align__(16) _Float16 hbuf[2][4][4][64];   // 4 KB [parity][layer][b][k]
    __shared__ float xall[4][SEQ];                         // 8 KB
    __shared__ float part[16][4][4][3];                    // 3 KB
    __shared__ float sconst[2];

    const int tid  = threadIdx.x;
    const int lane = tid & 63;
    const int w    = tid >> 6;        // wave 0..15
    const int ell  = w >> 2;          // layer
    const int om   = w & 3;           // tile quarter
    const int lam  = lane >> 4;
    const int bc   = lane & 15;
    const int br   = bc & 3;
    const int kq   = bc >> 2;         // owned tile within quarter
    const int bb   = blockIdx.x;

    // ---- stage x, zero h (both parities) ----
    for (int i = tid; i < 4 * SEQ; i += NTHR)
        xall[i >> 9][i & 511] = x[bb * 4 * SEQ + i];
    for (int i = tid; i < 2 * 4 * 4 * 64; i += NTHR)
        ((_Float16*)hbuf)[i] = (_Float16)0.0f;

    if (tid < 64) {
        float a = ln_g[tid] * Wout[tid];
        float b = ln_b[tid] * Wout[tid];
#pragma unroll
        for (int off = 32; off > 0; off >>= 1) {
            a += __shfl_xor(a, off, 64);
            b += __shfl_xor(b, off, 64);
        }
        if (tid == 0) { sconst[0] = a; sconst[1] = b; }
    }

    const float* Wp = (ell == 0) ? W0 : (ell == 1) ? W1 : (ell == 2) ? W2 : W3;
    const float* Bp = (ell == 0) ? B0 : (ell == 1) ? B1 : (ell == 2) ? B2 : B3;

    // ---- per-wave weights: 4 tiles, gate-permuted cols; biases in VGPR ----
    f16x8 wf[4][4];
    f32x4 biasv[4];
#pragma unroll
    for (int i = 0; i < 4; ++i) {
        const int T  = om * 4 + i;
        const int cA = (bc & 3) * 64 + T * 4 + (bc >> 2);
        if (ell == 0) {
#pragma unroll
            for (int kt = 0; kt < 2; ++kt)          // slots 0,1 = SELF h weights
#pragma unroll
                for (int e = 0; e < 8; ++e)
                    wf[i][kt][e] = (_Float16)W0[(1 + kt * 32 + lam * 8 + e) * 256 + cA];
#pragma unroll
            for (int e = 0; e < 8; ++e) { wf[i][2][e] = (_Float16)0.0f; wf[i][3][e] = (_Float16)0.0f; }
            if (lam == 0) wf[i][2][0] = (_Float16)W0[cA];   // x weight, one-hot A-frag
        } else {
#pragma unroll
            for (int kt = 0; kt < 4; ++kt)          // 0,1 = in-h; 2,3 = self-h
#pragma unroll
                for (int e = 0; e < 8; ++e)
                    wf[i][kt][e] = (_Float16)Wp[(kt * 32 + lam * 8 + e) * 256 + cA];
        }
#pragma unroll
        for (int r = 0; r < 4; ++r)
            biasv[i][r] = Bp[r * 64 + T * 4 + lam];
    }

    const int   mK  = (om * 4 + kq) * 4 + lam;
    const float gwK = ln_g[mK] * Wout[mK];
    const int   wrK = br * 128 + (((mK >> 3) ^ br) * 16) + (mK & 7) * 2;

    const int a0 = br * 128 + ((lam)     ^ br) * 16;
    const int a1 = br * 128 + ((4 + lam) ^ br) * 16;

    // layer-local LDS offsets (parity added per phase)
    const int inA0 = (ell == 0) ? a0 : (ell - 1) * 512 + a0;
    const int inA1 = (ell == 0) ? a1 : (ell - 1) * 512 + a1;
    const int sfA0 = ell * 512 + a0;
    const int sfA1 = ell * 512 + a1;
    const int wrKS = ell * 512 + wrK;
    const float* const xrow = &xall[br][0];

    const bool k1b = (bc & 4) != 0;
    const bool k2b = (bc & 8) != 0;
    const bool evenL = ((ell & 1) == 0);
    const int  skM   = (ell == 0) ? 0 : (ell == 1) ? 1 : (ell == 2) ? 3 : 4;

    f16x8 xf;
#pragma unroll
    for (int e = 0; e < 8; ++e) xf[e] = (_Float16)0.0f;

    float cstK = 0.0f;
    f32x4 A0 = {}, A1 = {}, A2 = {}, A3 = {};
    char* const hb = (char*)hbuf;

    __syncthreads();
    const float Sgw = sconst[0];
    const float Sbw = sconst[1] + bout[0];

    for (int k = 0; k <= 516; ++k) {
        const int tM = k - skM;

        // ---------- Sub A: even layers MFMA, odd layers gates ----------
        if (evenL) {
            if ((unsigned)tM < (unsigned)SEQ) MFMA_PHASE(tM)
        } else {
            const int tG = tM - 1;
            if ((unsigned)tG < (unsigned)SEQ) GATES_PHASE(tG)
        }
        __syncthreads();

        // ---------- Sub B: odd layers MFMA, even layers gates ----------
        if (evenL) {
            if ((unsigned)tM < (unsigned)SEQ) GATES_PHASE(tM)
        } else {
            if ((unsigned)tM < (unsigned)SEQ) MFMA_PHASE(tM)
        }
        if (ell == 3) {
            const int tg3 = k - 5;          // most recent completed L3 step
            if (tg3 >= 7 && (tg3 & 7) == 7) COMBINE3(tg3)
        }
        __syncthreads();
    }
}

extern "C" void kernel_launch(void* const* d_in, const int* in_sizes, int n_in,
                              void* d_out, int out_size, void* d_ws, size_t ws_size,
                              hipStream_t stream)
{
    const float* x    = (const float*)d_in[0];
    const float* W0   = (const float*)d_in[1];
    const float* B0   = (const float*)d_in[2];
    const float* W1   = (const float*)d_in[3];
    const float* B1   = (const float*)d_in[4];
    const float* W2   = (const float*)d_in[5];
    const float* B2   = (const float*)d_in[6];
    const float* W3   = (const float*)d_in[7];
    const float* B3   = (const float*)d_in[8];
    const float* ln_g = (const float*)d_in[9];
    const float* ln_b = (const float*)d_in[10];
    const float* Wout = (const float*)d_in[11];
    const float* bout = (const float*)d_in[12];
    float* out = (float*)d_out;

    lstm4_stag<<<NBLK, NTHR, 0, stream>>>(x, W0, B0, W1, B1, W2, B2, W3, B3,
                                          ln_g, ln_b, Wout, bout, out);
}

// Round 19
// 469.552 us; speedup vs baseline: 1.3937x; 1.3937x over previous
//
#include <hip/hip_runtime.h>

#define SEQ   512
#define NTHR  1024
#define NBLK  256

typedef _Float16 f16x8 __attribute__((ext_vector_type(8)));
typedef _Float16 f16x4 __attribute__((ext_vector_type(4)));
typedef float    f32x4 __attribute__((ext_vector_type(4)));

#define MFMA(a, b, c) __builtin_amdgcn_mfma_f32_16x16x32_f16((a), (b), (c), 0, 0, 0)

__device__ __forceinline__ float sig_(float x) {
    return __builtin_amdgcn_rcpf(1.0f + __builtin_amdgcn_exp2f(x * -1.4426950408889634f));
}
// sign-safe tanh via 2*sigmoid(2x)-1
__device__ __forceinline__ float tanh_(float x) {
    return fmaf(2.0f, __builtin_amdgcn_rcpf(1.0f + __builtin_amdgcn_exp2f(x * -2.8853900817779268f)), -1.0f);
}

// r17 SWP structure (549us winner) + two trims:
//  (1) layer-3 LN partials: per-tick shuffle-reduce (12 ds_swizzle + 6 fma)
//      replaced by ONE ds_write_b16 of hn into a 16-deep f16 history; the /8
//      COMBINE rebuilds sum/sumsq/proj from history (amortized).
//  (2) main loop peeled: ticks 6..509 run with no activity checks.
#define TICK(P0,P1,P2,P3, Q0,Q1,Q2,Q3, RD, WR, TAU, CHECKED)                   \
    {                                                                          \
        const int tB = (TAU) - 2 * ell;                                        \
        const bool actB = !(CHECKED) || ((unsigned)tB < (unsigned)SEQ);        \
        const bool actA = !(CHECKED) || ((unsigned)(tB + 1) < (unsigned)SEQ);  \
        if (actB) {   /* finish acc(t): self-MFMAs */                          \
            const f16x8 b2 = *(const f16x8*)(hb + (RD) + sfA0);                \
            const f16x8 b3 = *(const f16x8*)(hb + (RD) + sfA1);                \
            P0 = MFMA(wf[0][2], b2, P0);  P1 = MFMA(wf[1][2], b2, P1);         \
            P2 = MFMA(wf[2][2], b2, P2);  P3 = MFMA(wf[3][2], b2, P3);         \
            P0 = MFMA(wf[0][3], b3, P0);  P1 = MFMA(wf[1][3], b3, P1);         \
            P2 = MFMA(wf[2][3], b3, P2);  P3 = MFMA(wf[3][3], b3, P3);         \
        }                                                                      \
        if (actA) {   /* start acc(t+1): bias init + in-MFMAs */               \
            f16x8 b0, b1;                                                      \
            if (ell == 0) {                                                    \
                if (lam == 0) xf[0] = (_Float16)xrow[tB + 1];                  \
                b0 = xf; b1 = xf;      /* wf[i][1]==0 for ell 0 */             \
            } else {                                                           \
                b0 = *(const f16x8*)(hb + (RD) + inA0);                        \
                b1 = *(const f16x8*)(hb + (RD) + inA1);                        \
            }                                                                  \
            Q0 = *(const f32x4*)(bldsW + 0);                                   \
            Q1 = *(const f32x4*)(bldsW + 64);                                  \
            Q2 = *(const f32x4*)(bldsW + 128);                                 \
            Q3 = *(const f32x4*)(bldsW + 192);                                 \
            Q0 = MFMA(wf[0][0], b0, Q0);  Q1 = MFMA(wf[1][0], b0, Q1);         \
            Q2 = MFMA(wf[2][0], b0, Q2);  Q3 = MFMA(wf[3][0], b0, Q3);         \
            Q0 = MFMA(wf[0][1], b1, Q0);  Q1 = MFMA(wf[1][1], b1, Q1);         \
            Q2 = MFMA(wf[2][1], b1, Q2);  Q3 = MFMA(wf[3][1], b1, Q3);         \
        }                                                                      \
        if (actB) {   /* gates(t) from acc finished in phase B */              \
            const f32x4 s01 = k1b ? P1 : P0;                                   \
            const f32x4 s23 = k1b ? P3 : P2;                                   \
            const f32x4 aK  = k2b ? s23 : s01;                                 \
            const float gi = sig_(aK[0]);                                      \
            const float gf = sig_(aK[1]);                                      \
            const float gg = tanh_(aK[2]);                                     \
            const float go = sig_(aK[3]);                                      \
            cstK = fmaf(gf, cstK, gi * gg);                                    \
            const float hn = go * tanh_(cstK);                                 \
            *(_Float16*)(hb + (WR) + wrKS) = (_Float16)hn;                     \
            if (ell == 3)   /* raw f16 history store (one b16 write) */        \
                *(_Float16*)((char*)parth + ((tB & 15) << 9) + wrP) = (_Float16)hn; \
        }                                                                      \
        __syncthreads();                                                       \
        {                                                                      \
            const int t3 = (TAU) - 6;                                          \
            if (t3 >= 7 && (t3 & 7) == 7) COMBINE(t3)                          \
        }                                                                      \
    }

// LN + projection for the 8 steps ending at T3, from the f16 h-history.
// 512 threads: row = (slot-in-group sl, batch b), 16 sub-lanes reduce 64 m.
#define COMBINE(T3)                                                            \
    {                                                                          \
        if (tid < 512) {                                                       \
            const int row = tid >> 4, sub = tid & 15;                          \
            const int sl = row >> 2, b = row & 3;                              \
            const int slot = ((T3) - 7 + sl) & 15;                             \
            const int m0 = sub * 4;                                            \
            const f16x4 h4 = *(const f16x4*)&parth[slot][b][m0];               \
            const f32x4 g4 = *(const f32x4*)&gwlds[m0];                        \
            const float h0 = (float)h4[0], h1 = (float)h4[1];                  \
            const float h2 = (float)h4[2], h3 = (float)h4[3];                  \
            float u1 = (h0 + h1) + (h2 + h3);                                  \
            float u2 = fmaf(h0, h0, fmaf(h1, h1, fmaf(h2, h2, h3 * h3)));      \
            float u3 = fmaf(h0, g4[0], fmaf(h1, g4[1], fmaf(h2, g4[2], h3 * g4[3]))); \
            u1 += __shfl_xor(u1, 1, 64); u2 += __shfl_xor(u2, 1, 64); u3 += __shfl_xor(u3, 1, 64); \
            u1 += __shfl_xor(u1, 2, 64); u2 += __shfl_xor(u2, 2, 64); u3 += __shfl_xor(u3, 2, 64); \
            u1 += __shfl_xor(u1, 4, 64); u2 += __shfl_xor(u2, 4, 64); u3 += __shfl_xor(u3, 4, 64); \
            u1 += __shfl_xor(u1, 8, 64); u2 += __shfl_xor(u2, 8, 64); u3 += __shfl_xor(u3, 8, 64); \
            if (sub == 0) {                                                    \
                const float mu = u1 * (1.0f / 64.0f);                          \
                float var = fmaf(u2, 1.0f / 64.0f, -mu * mu);                  \
                var = fmaxf(var, 0.0f);                                        \
                const float rs = rsqrtf(var + 1e-5f);                          \
                out[(bb * 4 + b) * SEQ + ((T3) - 7) + sl] =                    \
                    fmaf(rs, fmaf(-mu, Sgw, u3), Sbw);                         \
            }                                                                  \
        }                                                                      \
    }

__global__ __launch_bounds__(NTHR, 4) void lstm4_swp2(
    const float* __restrict__ x,
    const float* __restrict__ W0, const float* __restrict__ B0,
    const float* __restrict__ W1, const float* __restrict__ B1,
    const float* __restrict__ W2, const float* __restrict__ B2,
    const float* __restrict__ W3, const float* __restrict__ B3,
    const float* __restrict__ ln_g, const float* __restrict__ ln_b,
    const float* __restrict__ Wout, const float* __restrict__ bout,
    float* __restrict__ out)
{
    __shared__ __align__(16) _Float16 hbuf[2][4][4][64];   // 4 KB [parity][layer][b][k]
    __shared__ float xall[4][SEQ];                         // 8 KB
    __shared__ __align__(16) _Float16 parth[16][4][64];    // 8 KB L3 h history
    __shared__ __align__(16) float blds[4][16][4][4];      // 4 KB biases [ell][T][lam][r]
    __shared__ __align__(16) float gwlds[64];              // ln_g*Wout table
    __shared__ float sconst[2];

    const int tid  = threadIdx.x;
    const int lane = tid & 63;
    const int w    = tid >> 6;        // wave 0..15
    const int ell  = w >> 2;          // layer
    const int om   = w & 3;           // tile quarter
    const int lam  = lane >> 4;
    const int bc   = lane & 15;
    const int br   = bc & 3;
    const int kq   = bc >> 2;         // owned tile within quarter
    const int bb   = blockIdx.x;

    // ---- stage x, zero h (both parities), biases -> LDS, gw table ----
    for (int i = tid; i < 4 * SEQ; i += NTHR)
        xall[i >> 9][i & 511] = x[bb * 4 * SEQ + i];
    for (int i = tid; i < 2 * 4 * 4 * 64; i += NTHR)
        ((_Float16*)hbuf)[i] = (_Float16)0.0f;
    {
        const int L = tid >> 8, idx = tid & 255;
        const int T = idx >> 4, lm = (idx >> 2) & 3, r = idx & 3;
        const float* Bp4 = (L == 0) ? B0 : (L == 1) ? B1 : (L == 2) ? B2 : B3;
        ((float*)blds)[tid] = Bp4[r * 64 + T * 4 + lm];
    }
    if (tid < 64) {
        const float a = ln_g[tid] * Wout[tid];
        gwlds[tid] = a;
        float sa = a, sb = ln_b[tid] * Wout[tid];
#pragma unroll
        for (int off = 32; off > 0; off >>= 1) {
            sa += __shfl_xor(sa, off, 64);
            sb += __shfl_xor(sb, off, 64);
        }
        if (tid == 0) { sconst[0] = sa; sconst[1] = sb; }
    }

    const float* Wp = (ell == 0) ? W0 : (ell == 1) ? W1 : (ell == 2) ? W2 : W3;

    // ---- weights: 4 tiles/wave, gate-permuted cols ----
    // wf[i][0..1] = in-frags (ell0: one-hot x + zero), wf[i][2..3] = self-frags
    f16x8 wf[4][4];
#pragma unroll
    for (int i = 0; i < 4; ++i) {
        const int T  = om * 4 + i;
        const int cA = (bc & 3) * 64 + T * 4 + (bc >> 2);
        if (ell == 0) {
#pragma unroll
            for (int kt = 0; kt < 2; ++kt)
#pragma unroll
                for (int e = 0; e < 8; ++e)
                    wf[i][2 + kt][e] = (_Float16)W0[(1 + kt * 32 + lam * 8 + e) * 256 + cA];
#pragma unroll
            for (int e = 0; e < 8; ++e) { wf[i][0][e] = (_Float16)0.0f; wf[i][1][e] = (_Float16)0.0f; }
            if (lam == 0) wf[i][0][0] = (_Float16)W0[cA];   // x weight, one-hot
        } else {
#pragma unroll
            for (int kt = 0; kt < 4; ++kt)        // 0,1 = in-h; 2,3 = self-h
#pragma unroll
                for (int e = 0; e < 8; ++e)
                    wf[i][kt][e] = (_Float16)Wp[(kt * 32 + lam * 8 + e) * 256 + cA];
        }
    }

    const int mK  = (om * 4 + kq) * 4 + lam;
    const int wrK = br * 128 + (((mK >> 3) ^ br) * 16) + (mK & 7) * 2;
    const int wrP = (br * 64 + mK) * 2;            // history byte offset (slot added/tick)

    const int a0 = br * 128 + ((lam)     ^ br) * 16;
    const int a1 = br * 128 + ((4 + lam) ^ br) * 16;

    const int inA0 = (ell == 0) ? a0 : (ell - 1) * 512 + a0;
    const int inA1 = (ell == 0) ? a1 : (ell - 1) * 512 + a1;
    const int sfA0 = ell * 512 + a0;
    const int sfA1 = ell * 512 + a1;
    const int wrKS = ell * 512 + wrK;
    const char* const bldsW = (const char*)blds + ell * 1024 + om * 256 + lam * 16;
    const float* const xrow = &xall[br][0];

    const bool k1b = (bc & 4) != 0;
    const bool k2b = (bc & 8) != 0;

    f16x8 xf;
#pragma unroll
    for (int e = 0; e < 8; ++e) xf[e] = (_Float16)0.0f;

    float cstK = 0.0f;
    char* const hb = (char*)hbuf;

    f32x4 aA0, aA1, aA2, aA3;      // acc set A (P at even ticks)
    f32x4 aB0, aB1, aB2, aB3;      // acc set B (P at odd ticks)

    __syncthreads();
    const float Sgw = sconst[0];
    const float Sbw = sconst[1] + bout[0];

    // ---- pre-loop: layer-0 seeds acc(0) in set A ----
    if (ell == 0) {
        if (lam == 0) xf[0] = (_Float16)xrow[0];
        const f16x8 b0 = xf;
        aA0 = *(const f32x4*)(bldsW + 0);
        aA1 = *(const f32x4*)(bldsW + 64);
        aA2 = *(const f32x4*)(bldsW + 128);
        aA3 = *(const f32x4*)(bldsW + 192);
        aA0 = MFMA(wf[0][0], b0, aA0);
        aA1 = MFMA(wf[1][0], b0, aA1);
        aA2 = MFMA(wf[2][0], b0, aA2);
        aA3 = MFMA(wf[3][0], b0, aA3);
    }

    // ---- prologue: j = 0..2 (checked) ----
    for (int j = 0; j < 3; ++j) {
        const int tau = 2 * j;
        TICK(aA0, aA1, aA2, aA3, aB0, aB1, aB2, aB3, 2048, 0, tau, true)
        TICK(aB0, aB1, aB2, aB3, aA0, aA1, aA2, aA3, 0, 2048, tau + 1, true)
    }
    // ---- main: j = 3..254 (tau 6..509, all waves fully active, unchecked) ----
    for (int j = 3; j < 255; ++j) {
        const int tau = 2 * j;
        TICK(aA0, aA1, aA2, aA3, aB0, aB1, aB2, aB3, 2048, 0, tau, false)
        TICK(aB0, aB1, aB2, aB3, aA0, aA1, aA2, aA3, 0, 2048, tau + 1, false)
    }
    // ---- epilogue: j = 255..258 (checked) ----
    for (int j = 255; j < 259; ++j) {
        const int tau = 2 * j;
        TICK(aA0, aA1, aA2, aA3, aB0, aB1, aB2, aB3, 2048, 0, tau, true)
        TICK(aB0, aB1, aB2, aB3, aA0, aA1, aA2, aA3, 0, 2048, tau + 1, true)
    }
}

extern "C" void kernel_launch(void* const* d_in, const int* in_sizes, int n_in,
                              void* d_out, int out_size, void* d_ws, size_t ws_size,
                              hipStream_t stream)
{
    const float* x    = (const float*)d_in[0];
    const float* W0   = (const float*)d_in[1];
    const float* B0   = (const float*)d_in[2];
    const float* W1   = (const float*)d_in[3];
    const float* B1   = (const float*)d_in[4];
    const float* W2   = (const float*)d_in[5];
    const float* B2   = (const float*)d_in[6];
    const float* W3   = (const float*)d_in[7];
    const float* B3   = (const float*)d_in[8];
    const float* ln_g = (const float*)d_in[9];
    const float* ln_b = (const float*)d_in[10];
    const float* Wout = (const float*)d_in[11];
    const float* bout = (const float*)d_in[12];
    float* out = (float*)d_out;

    lstm4_swp2<<<NBLK, NTHR, 0, stream>>>(x, W0, B0, W1, B1, W2, B2, W3, B3,
                                          ln_g, ln_b, Wout, bout, out);
}